// Round 21
// baseline (406.678 us; speedup 1.0000x reference)
//
#include <hip/hip_runtime.h>
#include <stdint.h>

#define BB 1024
#define SS 1024
#define TT 20

#define L2 16
#define C2 (SS / L2)  // 64 chunks for backtrack

#define RL(x, i) __uint_as_float(__builtin_amdgcn_readlane(__float_as_uint(x), i))

// Merge two (val,idx) candidates; 'a' side lower-index -> '>=' keeps FIRST max.
#define MERGE(vd, id, va, ia, vb, ib)  \
    {                                  \
        bool ge = (va) >= (vb);        \
        vd = ge ? (va) : (vb);         \
        id = ge ? (ia) : (ib);         \
    }

__device__ __forceinline__ void argmax20(
    float c0, float c1, float c2, float c3, float c4, float c5, float c6,
    float c7, float c8, float c9, float c10, float c11, float c12, float c13,
    float c14, float c15, float c16, float c17, float c18, float c19,
    float& best, int& bidx)
{
    float m0, m1, m2, m3, m4, m5, m6, m7, m8, m9;
    int i0, i1, i2, i3, i4, i5, i6, i7, i8, i9;
    MERGE(m0, i0, c0, 0, c1, 1);
    MERGE(m1, i1, c2, 2, c3, 3);
    MERGE(m2, i2, c4, 4, c5, 5);
    MERGE(m3, i3, c6, 6, c7, 7);
    MERGE(m4, i4, c8, 8, c9, 9);
    MERGE(m5, i5, c10, 10, c11, 11);
    MERGE(m6, i6, c12, 12, c13, 13);
    MERGE(m7, i7, c14, 14, c15, 15);
    MERGE(m8, i8, c16, 16, c17, 17);
    MERGE(m9, i9, c18, 18, c19, 19);

    float n0, n1, n2, n3, n4;
    int j0, j1, j2, j3, j4;
    MERGE(n0, j0, m0, i0, m1, i1);
    MERGE(n1, j1, m2, i2, m3, i3);
    MERGE(n2, j2, m4, i4, m5, i5);
    MERGE(n3, j3, m6, i6, m7, i7);
    MERGE(n4, j4, m8, i8, m9, i9);

    float p0, p1;
    int k0, k1;
    MERGE(p0, k0, n0, j0, n1, j1);
    MERGE(p1, k1, n2, j2, n3, j3);

    float q0;
    int l0;
    MERGE(q0, l0, p0, k0, p1, k1);

    MERGE(best, bidx, q0, l0, n4, j4);
}

// ---------------------------------------------------------------------------
// Forward Viterbi: TWO batches per wave (chains A,B interleaved) over the
// R10-proven 3x7 split-reduction. While chain A waits on its shuffle batch,
// chain B's instructions issue -> the ~400cy/step cross-lane latency is
// shared by two chains. Trans regs shared; per-chain score + prefetch.
// ---------------------------------------------------------------------------
__global__ __launch_bounds__(64) void fwd_kernel(
    const float* __restrict__ em,      // [B,S,T]
    const float* __restrict__ startt,  // [T]
    const float* __restrict__ endt,    // [T]
    const float* __restrict__ trans,   // [T,T]
    uint8_t* __restrict__ bp,          // [S,B,T] (s>=1 used)
    int* __restrict__ last_tag)        // [B]
{
    const int bA = 2 * blockIdx.x;
    const int bB = bA + 1;
    const int lane = threadIdx.x;
    const int p = (lane < 20) ? 0 : ((lane < 40) ? 1 : 2);  // group
    const int jr = lane - 20 * p;
    const int j = (jr < TT) ? jr : (TT - 1);
    const int ibase = 7 * p;

    const int i0 = ibase,     i1 = ibase + 1, i2 = ibase + 2, i3 = ibase + 3;
    const int i4 = ibase + 4, i5 = ibase + 5;
    const int i6 = (ibase + 6 > TT - 1) ? (TT - 1) : (ibase + 6);

    const float tr0 = trans[i0 * TT + j], tr1 = trans[i1 * TT + j];
    const float tr2 = trans[i2 * TT + j], tr3 = trans[i3 * TT + j];
    const float tr4 = trans[i4 * TT + j], tr5 = trans[i5 * TT + j];
    const float tr6 = trans[i6 * TT + j];

    const float* embA = em + (size_t)bA * SS * TT;
    const float* embB = em + (size_t)bB * SS * TT;
    float score_A = startt[j] + embA[j];
    float score_B = startt[j] + embB[j];

    uint8_t* bpbA = bp + (size_t)bA * TT + lane;
    uint8_t* bpbB = bp + (size_t)bB * TT + lane;

    const int l20 = (lane + 20) & 63;
    const int l40 = (lane + 40) & 63;

    // per-chain 16-deep named prefetch
    float fA0 = embA[(size_t)1 * TT + j],  fA1 = embA[(size_t)2 * TT + j];
    float fA2 = embA[(size_t)3 * TT + j],  fA3 = embA[(size_t)4 * TT + j];
    float fA4 = embA[(size_t)5 * TT + j],  fA5 = embA[(size_t)6 * TT + j];
    float fA6 = embA[(size_t)7 * TT + j],  fA7 = embA[(size_t)8 * TT + j];
    float fA8 = embA[(size_t)9 * TT + j],  fA9 = embA[(size_t)10 * TT + j];
    float fA10 = embA[(size_t)11 * TT + j], fA11 = embA[(size_t)12 * TT + j];
    float fA12 = embA[(size_t)13 * TT + j], fA13 = embA[(size_t)14 * TT + j];
    float fA14 = embA[(size_t)15 * TT + j], fA15 = embA[(size_t)16 * TT + j];
    float fB0 = embB[(size_t)1 * TT + j],  fB1 = embB[(size_t)2 * TT + j];
    float fB2 = embB[(size_t)3 * TT + j],  fB3 = embB[(size_t)4 * TT + j];
    float fB4 = embB[(size_t)5 * TT + j],  fB5 = embB[(size_t)6 * TT + j];
    float fB6 = embB[(size_t)7 * TT + j],  fB7 = embB[(size_t)8 * TT + j];
    float fB8 = embB[(size_t)9 * TT + j],  fB9 = embB[(size_t)10 * TT + j];
    float fB10 = embB[(size_t)11 * TT + j], fB11 = embB[(size_t)12 * TT + j];
    float fB12 = embB[(size_t)13 * TT + j], fB13 = embB[(size_t)14 * TT + j];
    float fB14 = embB[(size_t)15 * TT + j], fB15 = embB[(size_t)16 * TT + j];

// one interleaved step for BOTH chains at position 'scur'
#define VSTEP2_CORE(scur, FRA, FRB)                                         \
    {                                                                       \
        const float eA = FRA, eB = FRB;                                     \
        /* stage-1: issue both chains' 7-gathers back-to-back */            \
        const float sA0 = __shfl(score_A, i0, 64);                          \
        const float sA1 = __shfl(score_A, i1, 64);                          \
        const float sA2 = __shfl(score_A, i2, 64);                          \
        const float sA3 = __shfl(score_A, i3, 64);                          \
        const float sA4 = __shfl(score_A, i4, 64);                          \
        const float sA5 = __shfl(score_A, i5, 64);                          \
        const float sA6 = __shfl(score_A, i6, 64);                          \
        const float sB0 = __shfl(score_B, i0, 64);                          \
        const float sB1 = __shfl(score_B, i1, 64);                          \
        const float sB2 = __shfl(score_B, i2, 64);                          \
        const float sB3 = __shfl(score_B, i3, 64);                          \
        const float sB4 = __shfl(score_B, i4, 64);                          \
        const float sB5 = __shfl(score_B, i5, 64);                          \
        const float sB6 = __shfl(score_B, i6, 64);                          \
        /* chain A: local 7->1 tree */                                      \
        const float cA0 = sA0 + tr0, cA1 = sA1 + tr1, cA2 = sA2 + tr2;      \
        const float cA3 = sA3 + tr3, cA4 = sA4 + tr4, cA5 = sA5 + tr5;      \
        const float cA6 = sA6 + tr6;                                        \
        float aA0, aA1, aA2, bA0, bA1, rvA;                                 \
        int xA0, xA1, xA2, yA0, yA1, xrA;                                   \
        MERGE(aA0, xA0, cA0, i0, cA1, i1);                                  \
        MERGE(aA1, xA1, cA2, i2, cA3, i3);                                  \
        MERGE(aA2, xA2, cA4, i4, cA5, i5);                                  \
        MERGE(bA0, yA0, aA0, xA0, aA1, xA1);                                \
        MERGE(bA1, yA1, aA2, xA2, cA6, i6);                                 \
        MERGE(rvA, xrA, bA0, yA0, bA1, yA1);                                \
        /* chain A: stage-2 issue */                                        \
        const float g1vA = __shfl(rvA, l20, 64);                            \
        const int   g1xA = __shfl(xrA, l20, 64);                            \
        const float g2vA = __shfl(rvA, l40, 64);                            \
        const int   g2xA = __shfl(xrA, l40, 64);                            \
        /* chain B: local tree (hides A stage-2 latency) */                 \
        const float cB0 = sB0 + tr0, cB1 = sB1 + tr1, cB2 = sB2 + tr2;      \
        const float cB3 = sB3 + tr3, cB4 = sB4 + tr4, cB5 = sB5 + tr5;      \
        const float cB6 = sB6 + tr6;                                        \
        float aB0, aB1, aB2, bB0, bB1, rvB;                                 \
        int xB0, xB1, xB2, yB0, yB1, xrB;                                   \
        MERGE(aB0, xB0, cB0, i0, cB1, i1);                                  \
        MERGE(aB1, xB1, cB2, i2, cB3, i3);                                  \
        MERGE(aB2, xB2, cB4, i4, cB5, i5);                                  \
        MERGE(bB0, yB0, aB0, xB0, aB1, xB1);                                \
        MERGE(bB1, yB1, aB2, xB2, cB6, i6);                                 \
        MERGE(rvB, xrB, bB0, yB0, bB1, yB1);                                \
        /* chain B: stage-2 issue */                                        \
        const float g1vB = __shfl(rvB, l20, 64);                            \
        const int   g1xB = __shfl(xrB, l20, 64);                            \
        const float g2vB = __shfl(rvB, l40, 64);                            \
        const int   g2xB = __shfl(xrB, l40, 64);                            \
        /* finish A (partial lgkmcnt wait; B stage-2 still in flight) */    \
        float m01A, mfA;                                                    \
        int z01A, zfA;                                                      \
        MERGE(m01A, z01A, rvA, xrA, g1vA, g1xA);                            \
        MERGE(mfA, zfA, m01A, z01A, g2vA, g2xA);                            \
        score_A = mfA + eA;                                                 \
        if (lane < TT) bpbA[(size_t)(scur) * (BB * TT)] = (uint8_t)zfA;     \
        /* finish B */                                                      \
        float m01B, mfB;                                                    \
        int z01B, zfB;                                                      \
        MERGE(m01B, z01B, rvB, xrB, g1vB, g1xB);                            \
        MERGE(mfB, zfB, m01B, z01B, g2vB, g2xB);                            \
        score_B = mfB + eB;                                                 \
        if (lane < TT) bpbB[(size_t)(scur) * (BB * TT)] = (uint8_t)zfB;     \
    }

#define VSTEP2(scur, FRA, FRB)                                              \
    {                                                                       \
        VSTEP2_CORE(scur, FRA, FRB);                                        \
        const int sn_ = (scur) + 16;                                        \
        const int snc_ = sn_ > (SS - 1) ? (SS - 1) : sn_;                   \
        FRA = embA[(size_t)snc_ * TT + j];                                  \
        FRB = embB[(size_t)snc_ * TT + j];                                  \
    }

    for (int s = 1; s <= SS - 31; s += 16) {
        VSTEP2(s + 0, fA0, fB0);
        VSTEP2(s + 1, fA1, fB1);
        VSTEP2(s + 2, fA2, fB2);
        VSTEP2(s + 3, fA3, fB3);
        VSTEP2(s + 4, fA4, fB4);
        VSTEP2(s + 5, fA5, fB5);
        VSTEP2(s + 6, fA6, fB6);
        VSTEP2(s + 7, fA7, fB7);
        VSTEP2(s + 8, fA8, fB8);
        VSTEP2(s + 9, fA9, fB9);
        VSTEP2(s + 10, fA10, fB10);
        VSTEP2(s + 11, fA11, fB11);
        VSTEP2(s + 12, fA12, fB12);
        VSTEP2(s + 13, fA13, fB13);
        VSTEP2(s + 14, fA14, fB14);
        VSTEP2(s + 15, fA15, fB15);
    }

    VSTEP2_CORE(SS - 15, fA0, fB0);
    VSTEP2_CORE(SS - 14, fA1, fB1);
    VSTEP2_CORE(SS - 13, fA2, fB2);
    VSTEP2_CORE(SS - 12, fA3, fB3);
    VSTEP2_CORE(SS - 11, fA4, fB4);
    VSTEP2_CORE(SS - 10, fA5, fB5);
    VSTEP2_CORE(SS - 9, fA6, fB6);
    VSTEP2_CORE(SS - 8, fA7, fB7);
    VSTEP2_CORE(SS - 7, fA8, fB8);
    VSTEP2_CORE(SS - 6, fA9, fB9);
    VSTEP2_CORE(SS - 5, fA10, fB10);
    VSTEP2_CORE(SS - 4, fA11, fB11);
    VSTEP2_CORE(SS - 3, fA12, fB12);
    VSTEP2_CORE(SS - 2, fA13, fB13);
    VSTEP2_CORE(SS - 1, fA14, fB14);

    // final argmax per chain (readlane tree from lanes 0..19)
    {
        const float fin = score_A + endt[j];
        const float g0 = RL(fin, 0), g1 = RL(fin, 1), g2 = RL(fin, 2);
        const float g3 = RL(fin, 3), g4 = RL(fin, 4), g5 = RL(fin, 5);
        const float g6 = RL(fin, 6), g7 = RL(fin, 7), g8 = RL(fin, 8);
        const float g9 = RL(fin, 9), g10 = RL(fin, 10), g11 = RL(fin, 11);
        const float g12 = RL(fin, 12), g13 = RL(fin, 13), g14 = RL(fin, 14);
        const float g15 = RL(fin, 15), g16 = RL(fin, 16), g17 = RL(fin, 17);
        const float g18 = RL(fin, 18), g19 = RL(fin, 19);
        float best;
        int bidx;
        argmax20(g0, g1, g2, g3, g4, g5, g6, g7, g8, g9, g10, g11, g12, g13,
                 g14, g15, g16, g17, g18, g19, best, bidx);
        if (lane == 0) last_tag[bA] = bidx;
    }
    {
        const float fin = score_B + endt[j];
        const float g0 = RL(fin, 0), g1 = RL(fin, 1), g2 = RL(fin, 2);
        const float g3 = RL(fin, 3), g4 = RL(fin, 4), g5 = RL(fin, 5);
        const float g6 = RL(fin, 6), g7 = RL(fin, 7), g8 = RL(fin, 8);
        const float g9 = RL(fin, 9), g10 = RL(fin, 10), g11 = RL(fin, 11);
        const float g12 = RL(fin, 12), g13 = RL(fin, 13), g14 = RL(fin, 14);
        const float g15 = RL(fin, 15), g16 = RL(fin, 16), g17 = RL(fin, 17);
        const float g18 = RL(fin, 18), g19 = RL(fin, 19);
        float best;
        int bidx;
        argmax20(g0, g1, g2, g3, g4, g5, g6, g7, g8, g9, g10, g11, g12, g13,
                 g14, g15, g16, g17, g18, g19, best, bidx);
        if (lane == 0) last_tag[bB] = bidx;
    }
}

// ---------------------------------------------------------------------------
// Backtrack phase 1: compose per-chunk pointer maps.
// ---------------------------------------------------------------------------
__global__ void bt_compose(const uint8_t* __restrict__ bp, uint8_t* __restrict__ G)
{
    const int tid = blockIdx.x * blockDim.x + threadIdx.x;
    const int total = BB * (C2 - 1) * TT;
    if (tid >= total) return;
    const int j = tid % TT;
    const int r = tid / TT;
    const int c = 1 + (r % (C2 - 1));
    const int b = r / (C2 - 1);

    int t = j;
    const int hi = (c + 1) * L2 - 1;
#pragma unroll
    for (int k = 0; k < L2; ++k) {
        const int s = hi - k;
        t = bp[((size_t)s * BB + b) * TT + t];
    }
    G[((size_t)c * BB + b) * TT + j] = (uint8_t)t;
}

// ---------------------------------------------------------------------------
// Backtrack phase 2: serial scan over chunk boundaries (per batch).
// ---------------------------------------------------------------------------
__global__ void bt_scan(const uint8_t* __restrict__ G,
                        const int* __restrict__ last_tag,
                        int* __restrict__ xtag)
{
    const int b = blockIdx.x * blockDim.x + threadIdx.x;
    if (b >= BB) return;
    int x = last_tag[b];
    xtag[(size_t)(C2 - 1) * BB + b] = x;
    for (int c = C2 - 1; c >= 1; --c) {
        x = G[((size_t)c * BB + b) * TT + x];
        xtag[(size_t)(c - 1) * BB + b] = x;
    }
}

// ---------------------------------------------------------------------------
// Backtrack phase 3: expand within each chunk, write int32 tags.
// ---------------------------------------------------------------------------
__global__ void bt_expand(const uint8_t* __restrict__ bp,
                          const int* __restrict__ xtag,
                          int* __restrict__ out)
{
    const int tid = blockIdx.x * blockDim.x + threadIdx.x;
    if (tid >= BB * C2) return;
    const int c = tid % C2;
    const int b = tid / C2;

    int t = xtag[(size_t)c * BB + b];
    const int hi = (c + 1) * L2 - 1;
    int* ob = out + (size_t)b * SS;
    ob[hi] = t;
#pragma unroll
    for (int k = 0; k < L2 - 1; ++k) {
        const int s = hi - k;
        t = bp[((size_t)s * BB + b) * TT + t];
        ob[s - 1] = t;
    }
}

extern "C" void kernel_launch(void* const* d_in, const int* in_sizes, int n_in,
                              void* d_out, int out_size, void* d_ws, size_t ws_size,
                              hipStream_t stream) {
    const float* em = (const float*)d_in[0];   // emissions [B,S,T]
    const float* st = (const float*)d_in[1];   // start_transitions [T]
    const float* en = (const float*)d_in[2];   // end_transitions [T]
    const float* tr = (const float*)d_in[3];   // transitions [T,T]
    int* out = (int*)d_out;                    // [B,S] int32

    // workspace layout
    const size_t SBT = (size_t)SS * BB * TT;            // 20.97 MB backpointers
    uint8_t* bp = (uint8_t*)d_ws;
    int* last_tag = (int*)((char*)d_ws + SBT);          // 4 KB
    uint8_t* G = (uint8_t*)d_ws + SBT + 4096;           // C2*B*T = 1.31 MB
    int* xtag = (int*)((char*)d_ws + SBT + 4096 + (size_t)C2 * BB * TT);  // 256 KB

    fwd_kernel<<<BB / 2, 64, 0, stream>>>(em, st, en, tr, bp, last_tag);

    const int tot1 = BB * (C2 - 1) * TT;
    bt_compose<<<(tot1 + 255) / 256, 256, 0, stream>>>(bp, G);
    bt_scan<<<(BB + 255) / 256, 256, 0, stream>>>(G, last_tag, xtag);
    bt_expand<<<(BB * C2 + 255) / 256, 256, 0, stream>>>(bp, xtag, out);
}